// Round 12
// baseline (2445.139 us; speedup 1.0000x reference)
//
#include <hip/hip_runtime.h>

typedef float v2f __attribute__((ext_vector_type(2)));
typedef int   v2i __attribute__((ext_vector_type(2)));

#define QN 8192   // trajectories
#define MN 2048   // time steps
#define HN 64     // hidden units
#define UPL 2     // hidden units per lane (32 lanes per trajectory)

// DPP butterfly add within a 16-lane row (builtin form: compiler handles the
// GFX9 DPP read-after-write hazard legally; R11's raw-asm form corrupted data).
template <int CTRL>
__device__ __forceinline__ float dpp_add(float v) {
    int m = __builtin_amdgcn_update_dpp(__float_as_int(v), __float_as_int(v),
                                        CTRL, 0xf, 0xf, true);
    return v + __int_as_float(m);
}
#define DPP_QUAD_XOR1 0xB1   // quad_perm [1,0,3,2]
#define DPP_QUAD_XOR2 0x4E   // quad_perm [2,3,0,1]
#define DPP_HALF_MIRR 0x141  // row_half_mirror
#define DPP_ROW_MIRR  0x140  // row_mirror

// p[l] + p[l^32] in every lane (R6-proven): with both inputs = p,
// pr.x + pr.y == p[l] + p[l^32]. Pure VALU, pairs rows 0<->2 and 1<->3.
__device__ __forceinline__ float xor32_add(float p) {
    v2i pr = __builtin_amdgcn_permlane32_swap(__float_as_int(p), __float_as_int(p),
                                              false, false);
    return __int_as_float(pr.x) + __int_as_float(pr.y);
}

__device__ __forceinline__ v2f vfma(v2f a, v2f b, v2f c) {
    return __builtin_elementwise_fma(a, b, c);
}

__global__ __launch_bounds__(256, 4) void rk4_nss_kernel(
    const float* __restrict__ x0p,   // (Q,2)
    const float* __restrict__ up,    // (M,Q)
    const float* __restrict__ W1,    // (3,H)
    const float* __restrict__ b1,    // (H)
    const float* __restrict__ W2,    // (H,2)
    const float* __restrict__ b2,    // (2)
    float* __restrict__ out)         // (M,Q,2)
{
    const int tid    = blockIdx.x * 256 + threadIdx.x;
    const int lane64 = threadIdx.x & 63;
    const int wid    = tid >> 6;               // global wave id, 0..4095
    // Trajectory A = rows 0,2 (lanes 0-15,32-47); B = rows 1,3.
    // permlane32_swap pairs rows 0<->2 / 1<->3 = within-trajectory.
    const int group  = (lane64 >> 4) & 1;
    const int traj   = 2 * wid + group;
    const int s      = (lane64 & 15) + ((lane64 & 32) >> 1);  // unit idx 0..31

    const float SC = 2.8853900817779268f;  // 2*log2(e): e^{2x} = 2^(SC*x)
    const float CL = 27.0f;  // clamp (scaled): tanh(27/SC)==1.0f in f32;
                             // pair den-product <= ~2^54, cannot overflow.

    // Lane owns hidden units j = s, s+32, packed as one v2f -> pk_fma pre.
    // W1,b1 pre-scaled by SC; tanh = 1 - 2/(e^{2x}+1): "+1" folded into c0,c1
    // (applied once per step), accumulate inv*(-2*W2).
    v2f W10, W11, W12, BS;
    float w20n[UPL], w21n[UPL];
#pragma unroll
    for (int k = 0; k < UPL; ++k) {
        const int j = s + 32 * k;
        W10[k] = W1[j] * SC;
        W11[k] = W1[HN + j] * SC;
        W12[k] = W1[2 * HN + j] * SC;
        BS[k]  = b1[j] * SC;
        w20n[k] = -2.0f * W2[2 * j];
        w21n[k] = -2.0f * W2[2 * j + 1];
    }
    float c0 = b2[0], c1 = b2[1];
    for (int j = 0; j < HN; ++j) {   // init-time only; W2 is 512 B, cache-hot
        c0 += W2[2 * j];
        c1 += W2[2 * j + 1];
    }
    const float c0h = 0.5f * c0, c1h = 0.5f * c1;

    float xa = x0p[2 * traj];
    float xb = x0p[2 * traj + 1];

    float2* op = reinterpret_cast<float2*>(out) + 2 * wid;
    // Lanes 0 (group 0) and 16 (group 1) write their own trajectory's state:
    // adjacent float2 -> coalesced 16B per wave.
    const bool writer = ((lane64 & 47) == 0);

    v2f PB;  // u-dependent preactivation part, constant across the 4 fevals

    // Returns RAW p0,p1 (without +c): k_true = p + c, folded by the caller.
    auto feval = [&](float ia, float ib, float& p0o, float& p1o) {
        v2f IA = {ia, ia};
        v2f IB = {ib, ib};
        v2f PRE = vfma(W10, IA, vfma(W11, IB, PB));
        float den0 = __builtin_amdgcn_exp2f(__builtin_amdgcn_fmed3f(PRE.x, -CL, CL)) + 1.0f;
        float den1 = __builtin_amdgcn_exp2f(__builtin_amdgcn_fmed3f(PRE.y, -CL, CL)) + 1.0f;
        // Pair-batched reciprocal: exactly 1 rcp per lane per feval.
        float r    = __builtin_amdgcn_rcpf(den0 * den1);
        float inv0 = r * den1;
        float inv1 = r * den0;

        float p0 = fmaf(inv0, w20n[0], inv1 * w20n[1]);
        float p1 = fmaf(inv0, w21n[0], inv1 * w21n[1]);

        // 16-lane row reduce (4 DPP stages), then row<->row^2 via permlane32:
        // all 32 lanes of the trajectory end with the full sum (state stays
        // uniform across the trajectory's lanes -> no broadcast needed).
        p0 = dpp_add<DPP_QUAD_XOR1>(p0);  p1 = dpp_add<DPP_QUAD_XOR1>(p1);
        p0 = dpp_add<DPP_QUAD_XOR2>(p0);  p1 = dpp_add<DPP_QUAD_XOR2>(p1);
        p0 = dpp_add<DPP_HALF_MIRR>(p0);  p1 = dpp_add<DPP_HALF_MIRR>(p1);
        p0 = dpp_add<DPP_ROW_MIRR>(p0);   p1 = dpp_add<DPP_ROW_MIRR>(p1);
        p0 = xor32_add(p0);               p1 = xor32_add(p1);
        p0o = p0;
        p1o = p1;
    };

    // One RK4 step with the +c folds:
    //   k_i = p_i + c ;  x+0.5*k1 = (x+0.5c) + 0.5*p1 ;  x+k3 = (x+c) + p3
    //   x_new = x + (k1+2k2+2k3+k4)/6 = (x+c) + (p1+2p2+2p3+p4)/6
    auto step = [&](float u) {
        v2f UU = {u, u};
        PB = vfma(W12, UU, BS);

        const float xha = xa + c0h, xhb = xb + c1h;   // x + 0.5c
        const float xca = xa + c0,  xcb = xb + c1;    // x + c

        float p1a, p1b, p2a, p2b, p3a, p3b, p4a, p4b;
        feval(xa, xb, p1a, p1b);
        feval(fmaf(0.5f, p1a, xha), fmaf(0.5f, p1b, xhb), p2a, p2b);
        feval(fmaf(0.5f, p2a, xha), fmaf(0.5f, p2b, xhb), p3a, p3b);
        feval(xca + p3a, xcb + p3b, p4a, p4b);

        float ta = p2a + p3a, sa = p1a + p4a;
        xa = fmaf(1.0f / 6.0f, fmaf(2.0f, ta, sa), xca);
        float tb = p2b + p3b, sb = p1b + p4b;
        xb = fmaf(1.0f / 6.0f, fmaf(2.0f, tb, sb), xcb);
    };

    // Per-lane u load: all 32 lanes of a trajectory read the same address
    // (hardware broadcast); the wave's two addresses are adjacent dwords.
    float u0 = up[traj];
    float u1 = up[QN + traj];

    for (int t = 0; t < MN; t += 2) {
        // Prefetch 2 steps ahead (consumed next unrolled iteration).
        const float u2 = (t + 2 < MN) ? up[(t + 2) * QN + traj] : 0.0f;
        const float u3 = (t + 3 < MN) ? up[(t + 3) * QN + traj] : 0.0f;

        // Output is the state BEFORE the update.
        if (writer) op[group] = make_float2(xa, xb);
        op += QN;
        step(u0);

        if (writer) op[group] = make_float2(xa, xb);
        op += QN;
        step(u1);

        u0 = u2;
        u1 = u3;
    }
}

extern "C" void kernel_launch(void* const* d_in, const int* in_sizes, int n_in,
                              void* d_out, int out_size, void* d_ws, size_t ws_size,
                              hipStream_t stream) {
    const float* x0 = (const float*)d_in[0];
    const float* u  = (const float*)d_in[1];
    const float* W1 = (const float*)d_in[2];
    const float* b1 = (const float*)d_in[3];
    const float* W2 = (const float*)d_in[4];
    const float* b2 = (const float*)d_in[5];
    float* out = (float*)d_out;

    // 8192 trajectories, 2 per wave -> 4096 waves = 262144 threads
    // = 1024 blocks of 256 = 4 waves/SIMD (the wave-fill R6 proved, with
    // R8's per-wave instruction efficiency).
    const int threads = 256;
    const int blocks  = (QN / 2 * 64) / threads;
    rk4_nss_kernel<<<blocks, threads, 0, stream>>>(x0, u, W1, b1, W2, b2, out);
}

// Round 13
// 1789.939 us; speedup vs baseline: 1.3660x; 1.3660x over previous
//
#include <hip/hip_runtime.h>

typedef float v2f __attribute__((ext_vector_type(2)));

#define QN 8192   // trajectories
#define MN 2048   // time steps
#define HN 64     // hidden units
#define LPT 16    // lanes per trajectory (4 trajectories per wave)
#define UPL 4     // hidden units per lane

// DPP butterfly add (builtin form: compiler inserts the required GFX9 DPP
// hazard waits; raw-asm form in R11 corrupted data).
template <int CTRL>
__device__ __forceinline__ float dpp_add(float v) {
    int m = __builtin_amdgcn_update_dpp(__float_as_int(v), __float_as_int(v),
                                        CTRL, 0xf, 0xf, true);
    return v + __int_as_float(m);
}
#define DPP_QUAD_XOR1 0xB1   // quad_perm [1,0,3,2]
#define DPP_QUAD_XOR2 0x4E   // quad_perm [2,3,0,1]
#define DPP_HALF_MIRR 0x141  // row_half_mirror
#define DPP_ROW_MIRR  0x140  // row_mirror

__device__ __forceinline__ v2f vfma(v2f a, v2f b, v2f c) {
    return __builtin_elementwise_fma(a, b, c);
}

__global__ __launch_bounds__(256, 2) void rk4_nss_kernel(
    const float* __restrict__ x0p,   // (Q,2)
    const float* __restrict__ up,    // (M,Q)
    const float* __restrict__ W1,    // (3,H)
    const float* __restrict__ b1,    // (H)
    const float* __restrict__ W2,    // (H,2)
    const float* __restrict__ b2,    // (2)
    float* __restrict__ out)         // (M,Q,2)
{
    const int tid  = blockIdx.x * 256 + threadIdx.x;
    const int lane = threadIdx.x & (LPT - 1);
    const int traj = tid >> 4;

    const float SC = 2.8853900817779268f;  // 2*log2(e): e^{2x} = 2^(SC*x)
    const float CL = 27.0f;  // clamp (scaled): tanh(27/SC)==1.0f in f32;
                             // pair den-product <= ~2^54, cannot overflow.

    // Lane owns hidden units j = lane + k*16. PACKING: A-slots hold k={0,2},
    // B-slots hold k={1,3}, so every feval intermediate is a natural v_pk_*:
    //   DA=(den0,den2), DB=(den1,den3) -> DP=DA*DB=(d01,d23) [1 pk_mul]
    //   INVA=RV*DB=(inv0,inv2), INVB=RV*DA=(inv1,inv3)       [2 pk_mul]
    //   W2-trees accumulate (p0,p1) as one packed chain       [4 pk_fma]
    // W1,b1 pre-scaled by SC; tanh = 1 - 2/(e^{2x}+1): "+1" folded into c0,c1
    // (applied once per step), accumulate inv*(-2*W2).
    v2f W10A, W10B, W11A, W11B, W12A, W12B, BSA, BSB;
    v2f WK0, WK1, WK2, WK3;   // WKk = (-2*W2[j_k][0], -2*W2[j_k][1])
#pragma unroll
    for (int k = 0; k < UPL; ++k) {
        const int j = lane + k * LPT;
        const int sl = k >> 1;            // 0 for k={0,1}, 1 for k={2,3}
        if ((k & 1) == 0) {               // k = 0,2 -> A-pack slot sl
            W10A[sl] = W1[j] * SC;
            W11A[sl] = W1[HN + j] * SC;
            W12A[sl] = W1[2 * HN + j] * SC;
            BSA[sl]  = b1[j] * SC;
        } else {                          // k = 1,3 -> B-pack slot sl
            W10B[sl] = W1[j] * SC;
            W11B[sl] = W1[HN + j] * SC;
            W12B[sl] = W1[2 * HN + j] * SC;
            BSB[sl]  = b1[j] * SC;
        }
        v2f wk = {-2.0f * W2[2 * j], -2.0f * W2[2 * j + 1]};
        if (k == 0) WK0 = wk;
        else if (k == 1) WK1 = wk;
        else if (k == 2) WK2 = wk;
        else WK3 = wk;
    }
    float c0 = b2[0], c1 = b2[1];
    for (int j = 0; j < HN; ++j) {   // init-time only; W2 is 512 B, cache-hot
        c0 += W2[2 * j];
        c1 += W2[2 * j + 1];
    }
    const float c0h = 0.5f * c0, c1h = 0.5f * c1;

    float xa = x0p[2 * traj];
    float xb = x0p[2 * traj + 1];

    float2* op = reinterpret_cast<float2*>(out) + traj;
    const bool writer = (lane == 0);

    v2f PBA, PBB;  // u-dependent preactivation parts (A: k={0,2}, B: k={1,3})

    // Returns RAW p0,p1 (without +c): k_true = p + c, folded by the caller.
    auto feval = [&](float ia, float ib, float& p0o, float& p1o) {
        v2f IA = {ia, ia};
        v2f IB = {ib, ib};
        v2f PRA = vfma(W10A, IA, vfma(W11A, IB, PBA));   // (pre0, pre2)
        v2f PRB = vfma(W10B, IA, vfma(W11B, IB, PBB));   // (pre1, pre3)
        float e0 = __builtin_amdgcn_exp2f(__builtin_amdgcn_fmed3f(PRA.x, -CL, CL));
        float e2 = __builtin_amdgcn_exp2f(__builtin_amdgcn_fmed3f(PRA.y, -CL, CL));
        float e1 = __builtin_amdgcn_exp2f(__builtin_amdgcn_fmed3f(PRB.x, -CL, CL));
        float e3 = __builtin_amdgcn_exp2f(__builtin_amdgcn_fmed3f(PRB.y, -CL, CL));
        v2f DA = (v2f){e0, e2} + (v2f){1.0f, 1.0f};      // (den0, den2)
        v2f DB = (v2f){e1, e3} + (v2f){1.0f, 1.0f};      // (den1, den3)
        v2f DP = DA * DB;                                 // (d01, d23)
        // Pair-batched reciprocal (R3-proven): 2 independent rcp chains.
        v2f RV = {__builtin_amdgcn_rcpf(DP.x), __builtin_amdgcn_rcpf(DP.y)};
        v2f INVA = RV * DB;                               // (inv0, inv2)
        v2f INVB = RV * DA;                               // (inv1, inv3)

        // Packed W2 contraction: p = (p0, p1), inv_k broadcast via op_sel.
        v2f p = (v2f){INVA.x, INVA.x} * WK0;
        p = vfma((v2f){INVB.x, INVB.x}, WK1, p);
        p = vfma((v2f){INVA.y, INVA.y}, WK2, p);
        p = vfma((v2f){INVB.y, INVB.y}, WK3, p);

        float p0 = p.x, p1 = p.y;
        p0 = dpp_add<DPP_QUAD_XOR1>(p0);  p1 = dpp_add<DPP_QUAD_XOR1>(p1);
        p0 = dpp_add<DPP_QUAD_XOR2>(p0);  p1 = dpp_add<DPP_QUAD_XOR2>(p1);
        p0 = dpp_add<DPP_HALF_MIRR>(p0);  p1 = dpp_add<DPP_HALF_MIRR>(p1);
        p0 = dpp_add<DPP_ROW_MIRR>(p0);   p1 = dpp_add<DPP_ROW_MIRR>(p1);
        p0o = p0;
        p1o = p1;
    };

    // One RK4 step with the +c folds:
    //   k_i = p_i + c ;  x+0.5*k1 = (x+0.5c) + 0.5*p1 ;  x+k3 = (x+c) + p3
    //   x_new = x + (k1+2k2+2k3+k4)/6 = (x+c) + (p1+2p2+2p3+p4)/6
    auto step = [&](float u) {
        v2f UU = {u, u};
        PBA = vfma(W12A, UU, BSA);
        PBB = vfma(W12B, UU, BSB);

        const float xha = xa + c0h, xhb = xb + c1h;   // x + 0.5c
        const float xca = xa + c0,  xcb = xb + c1;    // x + c

        float p1a, p1b, p2a, p2b, p3a, p3b, p4a, p4b;
        feval(xa, xb, p1a, p1b);
        feval(fmaf(0.5f, p1a, xha), fmaf(0.5f, p1b, xhb), p2a, p2b);
        feval(fmaf(0.5f, p2a, xha), fmaf(0.5f, p2b, xhb), p3a, p3b);
        feval(xca + p3a, xcb + p3b, p4a, p4b);

        float ta = p2a + p3a, sa = p1a + p4a;
        xa = fmaf(1.0f / 6.0f, fmaf(2.0f, ta, sa), xca);
        float tb = p2b + p3b, sb = p1b + p4b;
        xb = fmaf(1.0f / 6.0f, fmaf(2.0f, tb, sb), xcb);
    };

    float u0 = up[traj];
    float u1 = up[QN + traj];

    for (int t = 0; t < MN; t += 2) {
        // Prefetch 2 steps ahead (consumed next unrolled iteration).
        const float u2 = (t + 2 < MN) ? up[(t + 2) * QN + traj] : 0.0f;
        const float u3 = (t + 3 < MN) ? up[(t + 3) * QN + traj] : 0.0f;

        // Output is the state BEFORE the update.
        if (writer) *op = make_float2(xa, xb);
        op += QN;
        step(u0);

        if (writer) *op = make_float2(xa, xb);
        op += QN;
        step(u1);

        u0 = u2;
        u1 = u3;
    }
}

extern "C" void kernel_launch(void* const* d_in, const int* in_sizes, int n_in,
                              void* d_out, int out_size, void* d_ws, size_t ws_size,
                              hipStream_t stream) {
    const float* x0 = (const float*)d_in[0];
    const float* u  = (const float*)d_in[1];
    const float* W1 = (const float*)d_in[2];
    const float* b1 = (const float*)d_in[3];
    const float* W2 = (const float*)d_in[4];
    const float* b2 = (const float*)d_in[5];
    float* out = (float*)d_out;

    // 8192 trajectories * 16 lanes = 131072 threads = 512 blocks of 256
    // = 2048 waves = exactly 2 waves/SIMD (the proven best quadrant).
    const int threads = 256;
    const int blocks  = (QN * LPT) / threads;
    rk4_nss_kernel<<<blocks, threads, 0, stream>>>(x0, u, W1, b1, W2, b2, out);
}